// Round 6
// baseline (115.608 us; speedup 1.0000x reference)
//
#include <hip/hip_runtime.h>

typedef __bf16 bf16;
typedef __attribute__((ext_vector_type(8))) __bf16 bf16x8;
typedef __attribute__((ext_vector_type(4))) float f32x4;
typedef __attribute__((ext_vector_type(16))) float f32x16;

#define DEV __device__ __forceinline__

DEV f32x4 mfma16(bf16x8 a, bf16x8 b, f32x4 c) {
  return __builtin_amdgcn_mfma_f32_16x16x32_bf16(a, b, c, 0, 0, 0);
}
DEV f32x16 mfma32(bf16x8 a, bf16x8 b, f32x16 c) {
  return __builtin_amdgcn_mfma_f32_32x32x16_bf16(a, b, c, 0, 0, 0);
}
// async global->LDS, 16B/lane; LDS dest must be wave-linear (base + lane*16)
DEV void gll16(const bf16* g, bf16* l) {
  __builtin_amdgcn_global_load_lds(
      (const __attribute__((address_space(1))) void*)g,
      (__attribute__((address_space(3))) void*)l, 16, 0, 0);
}
DEV unsigned cvtpk(float a, float b) {
  unsigned r;
  asm("v_cvt_pk_bf16_f32 %0, %1, %2" : "=v"(r) : "v"(a), "v"(b));
  return r;
}
// v_permlane32_swap_b32 vdst, vsrc : vdst.hi(lanes>=32) <-> vsrc.lo(lanes<32)
DEV void pl32swap(unsigned& x, unsigned& y) {
  asm("v_permlane32_swap_b32 %0, %1" : "+v"(x), "+v"(y));
}

// ---------------- fused prep: x cast + all weight transposes + bias concat ----------------
__global__ __launch_bounds__(256) void prep_k(
    const float* __restrict__ x, const float* __restrict__ wq,
    const float* __restrict__ wk, const float* __restrict__ wv,
    const float* __restrict__ wo, const float* __restrict__ w1,
    const float* __restrict__ w2, const float* __restrict__ bq,
    const float* __restrict__ bk, const float* __restrict__ bv,
    bf16* __restrict__ xb, bf16* __restrict__ wqkvT, bf16* __restrict__ woT,
    bf16* __restrict__ w1T, bf16* __restrict__ w2T, float* __restrict__ cb) {
  const int blk = blockIdx.x, tid = threadIdx.x;
  if (blk < 1024) {  // x -> bf16, vectorized
    int i = blk * 256 + tid;
    const float4* p = (const float4*)x + (size_t)i * 2;
    float4 a = p[0], b = p[1];
    bf16x8 o;
    o[0] = (bf16)a.x; o[1] = (bf16)a.y; o[2] = (bf16)a.z; o[3] = (bf16)a.w;
    o[4] = (bf16)b.x; o[5] = (bf16)b.y; o[6] = (bf16)b.z; o[7] = (bf16)b.w;
    ((bf16x8*)xb)[i] = o;
    return;
  }
  if (blk == 1792) {  // bias concat
    for (int i = tid; i < 1536; i += 256)
      cb[i] = i < 512 ? bq[i] : (i < 1024 ? bk[i - 512] : bv[i - 1024]);
    return;
  }
  // ---- 64x64 transpose tile through padded LDS ----
  __shared__ float tile[64][65];
  const int t = blk - 1024;
  const float* src;
  bf16* dst;
  int C, Rout, r0, c0;
  if (t < 192) {  // wq/wk/wv per-head [512][64] -> [64][512]
    int mat = t / 64, rem = t % 64, head = rem >> 3, rt = rem & 7;
    src = (mat == 0 ? wq : mat == 1 ? wk : wv) + head * 32768;
    dst = wqkvT + (size_t)(mat * 8 + head) * 32768;
    C = 64; Rout = 512; r0 = rt * 64; c0 = 0;
  } else if (t < 256) {  // wo [512][512] -> [512][512]^T
    int t2 = t - 192;
    src = wo; dst = woT; C = 512; Rout = 512;
    r0 = (t2 >> 3) * 64; c0 = (t2 & 7) * 64;
  } else if (t < 512) {  // w1 [512][2048] -> [2048][512]
    int t2 = t - 256;
    src = w1; dst = w1T; C = 2048; Rout = 512;
    r0 = (t2 >> 5) * 64; c0 = (t2 & 31) * 64;
  } else {  // w2 [2048][512] -> [512][2048]
    int t2 = t - 512;
    src = w2; dst = w2T; C = 512; Rout = 2048;
    r0 = (t2 >> 3) * 64; c0 = (t2 & 7) * 64;
  }
#pragma unroll
  for (int j = 0; j < 4; ++j) {
    int e = j * 256 + tid;
    int r = e >> 4, c4 = e & 15;
    float4 f = *(const float4*)(src + (size_t)(r0 + r) * C + c0 + c4 * 4);
    tile[r][c4 * 4 + 0] = f.x;
    tile[r][c4 * 4 + 1] = f.y;
    tile[r][c4 * 4 + 2] = f.z;
    tile[r][c4 * 4 + 3] = f.w;
  }
  __syncthreads();
  const int co = tid >> 2, rr0 = (tid & 3) * 16;
  bf16x8 o0, o1;
#pragma unroll
  for (int k = 0; k < 8; ++k) o0[k] = (bf16)tile[rr0 + k][co];
#pragma unroll
  for (int k = 0; k < 8; ++k) o1[k] = (bf16)tile[rr0 + 8 + k][co];
  bf16* dp = dst + (size_t)(c0 + co) * Rout + r0 + rr0;
  *(bf16x8*)dp = o0;
  *(bf16x8*)(dp + 8) = o1;
}

// V^T extract: qkv [4096][1536] (V at col 1024+h*64) -> vtb [bh][64 dh][2048 s]
__global__ __launch_bounds__(256) void vtrans_k(const bf16* __restrict__ qkv,
                                                bf16* __restrict__ vtb) {
  __shared__ bf16 tile[64 * 68];
  const int tid = threadIdx.x;
  const int s0 = blockIdx.x * 64;
  const int bh = blockIdx.y, b = bh >> 3, hh = bh & 7;
  const bf16* src = qkv + 1024 + hh * 64;
#pragma unroll
  for (int j = 0; j < 2; ++j) {
    int slot = j * 256 + tid;
    int r = slot >> 3, cc = slot & 7;
    *(bf16x8*)(tile + r * 68 + cc * 8) =
        *(const bf16x8*)(src + (size_t)(b * 2048 + s0 + r) * 1536 + cc * 8);
  }
  __syncthreads();
  const int w = tid >> 6, lane = tid & 63;
#pragma unroll
  for (int sb2 = 0; sb2 < 2; ++sb2) {
    int sb = w * 2 + sb2;
    bf16x8 v;
#pragma unroll
    for (int jj = 0; jj < 8; ++jj) v[jj] = tile[(sb * 8 + jj) * 68 + lane];
    *(bf16x8*)(vtb + (size_t)bh * 131072 + (size_t)lane * 2048 + s0 + sb * 8) = v;
  }
}

// ---------------- 128x64 tile GEMM, double-buffered 2-phase, optional split-K ----------------
// C[M][N] = A[M][K] * Bt[N][K]^T ; grid (M/128, N/64, nsplit), klen = K/nsplit
// EPI 0: f32 partial out (NO bias), slice z at outf + z*M*N
// EPI 1: bf16 relu(acc+bias)
// EPI 2: bf16 acc+bias, cols<512 scaled by 1/8 (QKV fused Q-scale)
template <int EPI>
__global__ __launch_bounds__(256) void gemmN64(
    const bf16* __restrict__ A, const bf16* __restrict__ Bt,
    const float* __restrict__ bias, float* __restrict__ outf,
    bf16* __restrict__ outb, int M, int N, int K, int klen) {
  __shared__ bf16 As[2][128 * 64];
  __shared__ bf16 Bs[2][64 * 64];
  const int tid = threadIdx.x;
  const int w = tid >> 6, l = tid & 63;
  const int lh = l & 15, lg = l >> 4;
  const int m0 = blockIdx.x * 128, n0 = blockIdx.y * 64;
  const int k0 = blockIdx.z * klen;
  const int mb = (w & 1) * 64, nb = (w >> 1) * 32;
  f32x4 acc[4][2] = {};
  auto stage = [&](int kt, int d) {
#pragma unroll
    for (int j = 0; j < 4; ++j) {
      int slot = j * 256 + tid;
      int r = slot >> 3, cc = slot & 7;
      int kk = kt + ((cc ^ (r & 7)) << 3);  // swizzle SOURCE, LDS stays linear
      gll16(A + (size_t)(m0 + r) * K + kk, As[d] + slot * 8);
    }
#pragma unroll
    for (int j = 0; j < 2; ++j) {
      int slot = j * 256 + tid;
      int r = slot >> 3, cc = slot & 7;
      int kk = kt + ((cc ^ (r & 7)) << 3);
      gll16(Bt + (size_t)(n0 + r) * K + kk, Bs[d] + slot * 8);
    }
  };
  stage(k0, 0);
  __syncthreads();  // drains vmcnt(0): buf0 ready
  const int nsteps = klen >> 6;
  for (int s = 0; s < nsteps; ++s) {
    const int d = s & 1;
    if (s + 1 < nsteps) stage(k0 + (s + 1) * 64, d ^ 1);  // issue BEFORE compute
#pragma unroll
    for (int kk = 0; kk < 2; ++kk) {
      bf16x8 af[4], bfr[2];
#pragma unroll
      for (int mi = 0; mi < 4; ++mi) {
        int r = mb + mi * 16 + lh;
        af[mi] = *(const bf16x8*)(As[d] + r * 64 + (((kk * 4 + lg) ^ (r & 7)) << 3));
      }
#pragma unroll
      for (int ni = 0; ni < 2; ++ni) {
        int r = nb + ni * 16 + lh;
        bfr[ni] = *(const bf16x8*)(Bs[d] + r * 64 + (((kk * 4 + lg) ^ (r & 7)) << 3));
      }
#pragma unroll
      for (int mi = 0; mi < 4; ++mi)
#pragma unroll
        for (int ni = 0; ni < 2; ++ni)
          acc[mi][ni] = mfma16(af[mi], bfr[ni], acc[mi][ni]);
    }
    __syncthreads();  // one drain+barrier per K-step (next buf ready, readers done)
  }
  float* op = (EPI == 0) ? outf + (size_t)blockIdx.z * M * N : nullptr;
#pragma unroll
  for (int mi = 0; mi < 4; ++mi)
#pragma unroll
    for (int ni = 0; ni < 2; ++ni)
#pragma unroll
      for (int i = 0; i < 4; ++i) {
        int row = m0 + mb + mi * 16 + lg * 4 + i;  // C/D: col=lane&15, row=(lane>>4)*4+reg
        int col = n0 + nb + ni * 16 + lh;
        float v = acc[mi][ni][i];
        if (EPI == 0) {
          op[(size_t)row * N + col] = v;
        } else if (EPI == 1) {
          v += bias[col];
          outb[(size_t)row * N + col] = (bf16)fmaxf(v, 0.f);
        } else {
          v += bias[col];
          outb[(size_t)row * N + col] = (bf16)(col < 512 ? v * 0.125f : v);
        }
      }
}

// ---------------- flash attention fwd ----------------
// grid (16 qtiles, 16 bh); 8 waves. Waves 0-3: keys [0,1024), waves 4-7: [1024,2048),
// pair (w, w+4) shares q-rows qtile*128 + (w&3)*32 .. +32. 32x32x16 MFMA,
// swapped QK^T (S^T = K·Q^T), in-register softmax, P via cvt_pk+permlane32_swap.
__global__ __launch_bounds__(512) void attn_fwd2(
    const bf16* __restrict__ qkv,  // [4096][1536], Q pre-scaled by 1/8
    const bf16* __restrict__ vtb,  // [bh][64][2048]
    bf16* __restrict__ Y) {        // [4096][512]
  __shared__ __align__(16) char lds[65536];
  const int tid = threadIdx.x;
  const int w = tid >> 6, lane = tid & 63;
  const int l31 = lane & 31, h = lane >> 5;
  const int bh = blockIdx.y, b = bh >> 3, hh = bh & 7;
  const int qtile = blockIdx.x;
  const int half = w >> 2, wp = w & 3;
  const int q0 = qtile * 128 + wp * 32;
  const int tl = tid & 255, sh = tid >> 8;

  // Q B-frags: qf[g] = Q[q0+l31][g*16 + h*8 .. +8]
  bf16x8 qf[4];
  {
    const size_t rowQ = (size_t)(b * 2048 + q0 + l31) * 1536 + hh * 64;
#pragma unroll
    for (int g = 0; g < 4; ++g)
      qf[g] = *(const bf16x8*)(qkv + rowQ + g * 16 + h * 8);
  }
  const bf16* Kp = qkv + 512 + hh * 64;
  const bf16* Vp = vtb + (size_t)bh * 131072;

  f32x16 oacc[2] = {};
  float m_run = -1e30f, l_run = 0.f;

#define KBUF(d, hf) ((bf16*)(lds + (d) * 32768 + (hf) * 16384))
#define VBUF(d, hf) ((bf16*)(lds + (d) * 32768 + (hf) * 16384 + 8192))

  // stage iteration i into dbuf d (each half stages its own K,V^T 64x64 tiles)
  auto stage = [&](int i, int d) {
    const int k0 = sh * 1024 + i * 64;
#pragma unroll
    for (int j = 0; j < 2; ++j) {
      int slot = j * 256 + tl;
      int r = slot >> 3, cc = slot & 7;
      gll16(Kp + (size_t)(b * 2048 + k0 + r) * 1536 + ((cc ^ (r & 7)) << 3),
            KBUF(d, sh) + slot * 8);
      gll16(Vp + (size_t)r * 2048 + k0 + ((cc ^ (r & 7)) << 3),
            VBUF(d, sh) + slot * 8);
    }
  };

  stage(0, 0);
  __syncthreads();
  for (int i = 0; i < 16; ++i) {
    const int d = i & 1;
    if (i < 15) stage(i + 1, d ^ 1);
    const bf16* Kt = KBUF(d, half);
    const bf16* Vt = VBUF(d, half);
    // S^T tiles [32 keys x 32 q], keys kt*32 + (r&3)+8*(r>>2)+4h
    f32x16 st[2];
    __builtin_amdgcn_s_setprio(1);
#pragma unroll
    for (int kt = 0; kt < 2; ++kt) {
      f32x16 z = {};
      const int r = kt * 32 + l31;
#pragma unroll
      for (int g = 0; g < 4; ++g) {
        bf16x8 kf = *(const bf16x8*)(Kt + r * 64 + (((2 * g + h) ^ (r & 7)) << 3));
        z = mfma32(kf, qf[g], z);
      }
      st[kt] = z;
    }
    __builtin_amdgcn_s_setprio(0);
    // online softmax over 64 keys (32 regs/lane + cross-half)
    float mx = -1e30f;
#pragma unroll
    for (int kt = 0; kt < 2; ++kt)
#pragma unroll
      for (int r = 0; r < 16; ++r) mx = fmaxf(mx, st[kt][r]);
    mx = fmaxf(mx, __shfl_xor(mx, 32, 64));
    const float m_new = fmaxf(m_run, mx);
    const float scl = __expf(m_run - m_new);
    m_run = m_new;
    float ps = 0.f;
#pragma unroll
    for (int kt = 0; kt < 2; ++kt)
#pragma unroll
      for (int r = 0; r < 16; ++r) {
        float e = __expf(st[kt][r] - m_new);
        st[kt][r] = e;
        ps += e;
      }
    ps += __shfl_xor(ps, 32, 64);
    l_run = l_run * scl + ps;
    oacc[0] = oacc[0] * scl;
    oacc[1] = oacc[1] * scl;
    // pack P^T B-frags: per 16-key group, dwords {a0,a1,b0,b1}
    // pl32swap(a,b): a.hi <-> b.lo  =>  a: h0 keeps (0,1), h1 gets (8,9);
    //                                   b: h0 gets (4,5), h1 keeps (12,13).
    bf16x8 pf[4];
#pragma unroll
    for (int kt = 0; kt < 2; ++kt)
#pragma unroll
      for (int g = 0; g < 2; ++g) {
        unsigned a0 = cvtpk(st[kt][8 * g + 0], st[kt][8 * g + 1]);
        unsigned a1 = cvtpk(st[kt][8 * g + 2], st[kt][8 * g + 3]);
        unsigned b0 = cvtpk(st[kt][8 * g + 4], st[kt][8 * g + 5]);
        unsigned b1 = cvtpk(st[kt][8 * g + 6], st[kt][8 * g + 7]);
        pl32swap(a0, b0);
        pl32swap(a1, b1);
        union { unsigned u[4]; bf16x8 v; } pk;
        pk.u[0] = a0; pk.u[1] = a1; pk.u[2] = b0; pk.u[3] = b1;
        pf[kt * 2 + g] = pk.v;
      }
    // PV: Y^T[dh][q] += V^T frag x P frag
    __builtin_amdgcn_s_setprio(1);
#pragma unroll
    for (int t = 0; t < 2; ++t) {
      const int r = t * 32 + l31;
#pragma unroll
      for (int kg = 0; kg < 4; ++kg) {
        bf16x8 vf = *(const bf16x8*)(Vt + r * 64 + (((2 * kg + h) ^ (r & 7)) << 3));
        oacc[t] = mfma32(vf, pf[kg], oacc[t]);
      }
    }
    __builtin_amdgcn_s_setprio(0);
    __syncthreads();
  }

  // ---- merge split-KV halves ----
  // lds reuse: Ost [pair p][8 chunks][64 lanes][16B] @0 (32KB); m,l @32768 (2KB); Ytile @34816
  if (half == 1) {
    char* ob = lds + wp * 8192;
#pragma unroll
    for (int t = 0; t < 2; ++t)
#pragma unroll
      for (int c = 0; c < 4; ++c) {
        f32x4 v4 = {oacc[t][c * 4 + 0], oacc[t][c * 4 + 1],
                    oacc[t][c * 4 + 2], oacc[t][c * 4 + 3]};
        *(f32x4*)(ob + (t * 4 + c) * 1024 + lane * 16) = v4;
      }
    ((float2*)(lds + 32768))[wp * 64 + lane] = make_float2(m_run, l_run);
  }
  __syncthreads();
  bf16* Yt = (bf16*)(lds + 34816);  // [128 q][72 dh]
  if (half == 0) {
    float2 ml2 = ((const float2*)(lds + 32768))[wp * 64 + lane];
    const float mstar = fmaxf(m_run, ml2.x);
    const float e1 = __expf(m_run - mstar), e2 = __expf(ml2.x - mstar);
    const float lstar = l_run * e1 + ml2.y * e2;
    const float r1 = e1 / lstar, r2 = e2 / lstar;
    const char* ob = lds + wp * 8192;
#pragma unroll
    for (int t = 0; t < 2; ++t)
#pragma unroll
      for (int c = 0; c < 4; ++c) {
        f32x4 v4 = *(const f32x4*)(ob + (t * 4 + c) * 1024 + lane * 16);
#pragma unroll
        for (int j = 0; j < 4; ++j)
          oacc[t][c * 4 + j] = oacc[t][c * 4 + j] * r1 + v4[j] * r2;
      }
#pragma unroll
    for (int t = 0; t < 2; ++t)
#pragma unroll
      for (int r = 0; r < 16; ++r) {
        int dh = (r & 3) + 8 * (r >> 2) + 4 * h + 32 * t;
        Yt[(wp * 32 + l31) * 72 + dh] = (bf16)oacc[t][r];
      }
  }
  __syncthreads();
#pragma unroll
  for (int it = 0; it < 2; ++it) {
    int s = it * 512 + tid;
    int ql = s >> 3, cbk = s & 7;
    bf16x8 v = *(const bf16x8*)(Yt + ql * 72 + cbk * 8);
    *(bf16x8*)(Y + (size_t)(b * 2048 + qtile * 128 + ql) * 512 + hh * 64 + cbk * 8) = v;
  }
#undef KBUF
#undef VBUF
}

// ---------------- fused: sum 2 split-K partials + bias + f32 residual -> LN -> bf16 ----------------
__global__ __launch_bounds__(256) void add_ln1_k(
    const float* __restrict__ P,  // [2][4096][512]
    const float* __restrict__ xres, const float* __restrict__ bias,
    const float* __restrict__ gamma, const float* __restrict__ beta,
    bf16* __restrict__ outb) {
  const int row = blockIdx.x, tid = threadIdx.x;
  const size_t base = (size_t)row * 512;
  const float2 p0 = ((const float2*)(P + base))[tid];
  const float2 p1 = ((const float2*)(P + 2097152 + base))[tid];
  const float2 xr = ((const float2*)(xres + base))[tid];
  const int c = tid * 2;
  float s0 = p0.x + p1.x + bias[c] + xr.x;
  float s1 = p0.y + p1.y + bias[c + 1] + xr.y;
  float sum = s0 + s1;
#pragma unroll
  for (int m = 1; m < 64; m <<= 1) sum += __shfl_xor(sum, m, 64);
  __shared__ float part[4], part2[4];
  const int w = tid >> 6, l = tid & 63;
  if (l == 0) part[w] = sum;
  __syncthreads();
  const float mean = (part[0] + part[1] + part[2] + part[3]) * (1.f / 512.f);
  const float d0 = s0 - mean, d1 = s1 - mean;
  float vs = d0 * d0 + d1 * d1;
#pragma unroll
  for (int m = 1; m < 64; m <<= 1) vs += __shfl_xor(vs, m, 64);
  if (l == 0) part2[w] = vs;
  __syncthreads();
  const float var = (part2[0] + part2[1] + part2[2] + part2[3]) * (1.f / 512.f);
  const float inv = rsqrtf(var);
  outb[base + c] = (bf16)(gamma[c] * (d0 * inv) + beta[c]);
  outb[base + c + 1] = (bf16)(gamma[c + 1] * (d1 * inv) + beta[c + 1]);
}

// ---------------- fused: sum 2 partials + bias + bf16 residual -> LN -> f32 out ----------------
__global__ __launch_bounds__(256) void add_ln2_k(
    const float* __restrict__ P,  // [2][4096][512]
    const bf16* __restrict__ rres, const float* __restrict__ bias,
    const float* __restrict__ gamma, const float* __restrict__ beta,
    float* __restrict__ outf) {
  const int row = blockIdx.x, tid = threadIdx.x;
  const size_t base = (size_t)row * 512;
  const float2 p0 = ((const float2*)(P + base))[tid];
  const float2 p1 = ((const float2*)(P + 2097152 + base))[tid];
  const int c = tid * 2;
  float s0 = p0.x + p1.x + bias[c] + (float)rres[base + c];
  float s1 = p0.y + p1.y + bias[c + 1] + (float)rres[base + c + 1];
  float sum = s0 + s1;
#pragma unroll
  for (int m = 1; m < 64; m <<= 1) sum += __shfl_xor(sum, m, 64);
  __shared__ float part[4], part2[4];
  const int w = tid >> 6, l = tid & 63;
  if (l == 0) part[w] = sum;
  __syncthreads();
  const float mean = (part[0] + part[1] + part[2] + part[3]) * (1.f / 512.f);
  const float d0 = s0 - mean, d1 = s1 - mean;
  float vs = d0 * d0 + d1 * d1;
#pragma unroll
  for (int m = 1; m < 64; m <<= 1) vs += __shfl_xor(vs, m, 64);
  if (l == 0) part2[w] = vs;
  __syncthreads();
  const float var = (part2[0] + part2[1] + part2[2] + part2[3]) * (1.f / 512.f);
  const float inv = rsqrtf(var);
  ((float2*)(outf + base))[tid] =
      make_float2(gamma[c] * (d0 * inv) + beta[c], gamma[c + 1] * (d1 * inv) + beta[c + 1]);
}

// ---------------- launch ----------------
extern "C" void kernel_launch(void* const* d_in, const int* in_sizes, int n_in,
                              void* d_out, int out_size, void* d_ws, size_t ws_size,
                              hipStream_t stream) {
  const float* x = (const float*)d_in[0];
  const float* wq = (const float*)d_in[1];
  const float* bq = (const float*)d_in[2];
  const float* wk = (const float*)d_in[3];
  const float* bk = (const float*)d_in[4];
  const float* wv = (const float*)d_in[5];
  const float* bv = (const float*)d_in[6];
  const float* wo = (const float*)d_in[7];
  const float* bo = (const float*)d_in[8];
  const float* g1 = (const float*)d_in[9];
  const float* be1 = (const float*)d_in[10];
  const float* w1 = (const float*)d_in[11];
  const float* b1 = (const float*)d_in[12];
  const float* w2 = (const float*)d_in[13];
  const float* b2 = (const float*)d_in[14];
  const float* g2 = (const float*)d_in[15];
  const float* be2 = (const float*)d_in[16];

  char* ws = (char*)d_ws;
  // layout (aliasing by liveness):
  bf16* xb    = (bf16*)(ws + 0);          // 4MB, cast -> QKV gemm
  bf16* y1b   = (bf16*)(ws + 0);          // 4MB, LN1 out -> FFN1 in, LN2 residual (aliases xb)
  bf16* wqkvT = (bf16*)(ws + 4194304);    // 1.5MB [1536][512]
  bf16* woT   = (bf16*)(ws + 5767168);    // 0.5MB
  bf16* w1T   = (bf16*)(ws + 6291456);    // 2MB
  bf16* w2T   = (bf16*)(ws + 8388608);    // 2MB
  float* cb   = (float*)(ws + 10485760);  // 8KB
  bf16* qkvb  = (bf16*)(ws + 10493952);   // 12MB [4096][1536], QKV -> attn
  float* t0   = (float*)(ws + 10493952);  // 16MB [2][4096][512] O-proj partials (alias qkvb, post-attn)
  bf16* f1    = (bf16*)(ws + 10493952);   // 16MB [4096][2048] FFN1 out (alias t0, post-LN1)
  bf16* vtb   = (bf16*)(ws + 23078656);   // 4MB [16][64][2048], vtrans -> attn
  bf16* yb    = (bf16*)(ws + 27272960);   // 4MB [4096][512], attn -> O-proj
  float* f2   = (float*)(ws + 27272960);  // 16MB [2][4096][512] FFN2 partials (alias yb, post-Oproj)

  prep_k<<<1793, 256, 0, stream>>>(x, wq, wk, wv, wo, w1, w2, bq, bk, bv,
                                   xb, wqkvT, woT, w1T, w2T, cb);

  // QKV: 768 blocks
  gemmN64<2><<<dim3(32, 24, 1), 256, 0, stream>>>(xb, wqkvT, cb, nullptr, qkvb,
                                                  4096, 1536, 512, 512);
  vtrans_k<<<dim3(32, 16), 256, 0, stream>>>(qkvb, vtb);
  attn_fwd2<<<dim3(16, 16), 512, 0, stream>>>(qkvb, vtb, yb);
  // O-proj: split-K x2, 512 blocks, partials (bias added in LN1)
  gemmN64<0><<<dim3(32, 8, 2), 256, 0, stream>>>(yb, woT, nullptr, t0, nullptr,
                                                 4096, 512, 512, 256);
  add_ln1_k<<<4096, 256, 0, stream>>>(t0, x, bo, g1, be1, y1b);
  // FFN1: 1024 blocks
  gemmN64<1><<<dim3(32, 32, 1), 256, 0, stream>>>(y1b, w1T, b1, nullptr, f1,
                                                  4096, 2048, 512, 512);
  // FFN2: split-K x2, 512 blocks, partials (bias added in LN2)
  gemmN64<0><<<dim3(32, 8, 2), 256, 0, stream>>>(f1, w2T, nullptr, f2, nullptr,
                                                 4096, 512, 2048, 1024);
  add_ln2_k<<<4096, 256, 0, stream>>>(f2, y1b, b2, g2, be2, (float*)d_out);
}

// Round 7
// 114.120 us; speedup vs baseline: 1.0130x; 1.0130x over previous
//
#include <hip/hip_runtime.h>

typedef __bf16 bf16;
typedef __attribute__((ext_vector_type(8))) __bf16 bf16x8;
typedef __attribute__((ext_vector_type(4))) float f32x4;
typedef __attribute__((ext_vector_type(16))) float f32x16;

#define DEV __device__ __forceinline__
#define VMCNT(n) asm volatile("s_waitcnt vmcnt(" #n ")" ::: "memory")

DEV f32x4 mfma16(bf16x8 a, bf16x8 b, f32x4 c) {
  return __builtin_amdgcn_mfma_f32_16x16x32_bf16(a, b, c, 0, 0, 0);
}
DEV f32x16 mfma32(bf16x8 a, bf16x8 b, f32x16 c) {
  return __builtin_amdgcn_mfma_f32_32x32x16_bf16(a, b, c, 0, 0, 0);
}
// async global->LDS, 16B/lane; LDS dest must be wave-linear (base + lane*16)
DEV void gll16(const bf16* g, bf16* l) {
  __builtin_amdgcn_global_load_lds(
      (const __attribute__((address_space(1))) void*)g,
      (__attribute__((address_space(3))) void*)l, 16, 0, 0);
}
DEV unsigned cvtpk(float a, float b) {
  unsigned r;
  asm("v_cvt_pk_bf16_f32 %0, %1, %2" : "=v"(r) : "v"(a), "v"(b));
  return r;
}
// v_permlane32_swap_b32 vdst, vsrc : vdst.hi(lanes>=32) <-> vsrc.lo(lanes<32)
DEV void pl32swap(unsigned& x, unsigned& y) {
  asm("v_permlane32_swap_b32 %0, %1" : "+v"(x), "+v"(y));
}

// ---------------- fused prep: x cast + all weight transposes + bias concat ----------------
__global__ __launch_bounds__(256) void prep_k(
    const float* __restrict__ x, const float* __restrict__ wq,
    const float* __restrict__ wk, const float* __restrict__ wv,
    const float* __restrict__ wo, const float* __restrict__ w1,
    const float* __restrict__ w2, const float* __restrict__ bq,
    const float* __restrict__ bk, const float* __restrict__ bv,
    bf16* __restrict__ xb, bf16* __restrict__ wqkvT, bf16* __restrict__ woT,
    bf16* __restrict__ w1T, bf16* __restrict__ w2T, float* __restrict__ cb) {
  const int blk = blockIdx.x, tid = threadIdx.x;
  if (blk < 1024) {  // x -> bf16, vectorized
    int i = blk * 256 + tid;
    const float4* p = (const float4*)x + (size_t)i * 2;
    float4 a = p[0], b = p[1];
    bf16x8 o;
    o[0] = (bf16)a.x; o[1] = (bf16)a.y; o[2] = (bf16)a.z; o[3] = (bf16)a.w;
    o[4] = (bf16)b.x; o[5] = (bf16)b.y; o[6] = (bf16)b.z; o[7] = (bf16)b.w;
    ((bf16x8*)xb)[i] = o;
    return;
  }
  if (blk == 1792) {  // bias concat
    for (int i = tid; i < 1536; i += 256)
      cb[i] = i < 512 ? bq[i] : (i < 1024 ? bk[i - 512] : bv[i - 1024]);
    return;
  }
  // ---- 64x64 transpose tile through padded LDS ----
  __shared__ float tile[64][65];
  const int t = blk - 1024;
  const float* src;
  bf16* dst;
  int C, Rout, r0, c0;
  if (t < 192) {  // wq/wk/wv per-head [512][64] -> [64][512]
    int mat = t / 64, rem = t % 64, head = rem >> 3, rt = rem & 7;
    src = (mat == 0 ? wq : mat == 1 ? wk : wv) + head * 32768;
    dst = wqkvT + (size_t)(mat * 8 + head) * 32768;
    C = 64; Rout = 512; r0 = rt * 64; c0 = 0;
  } else if (t < 256) {  // wo [512][512] -> [512][512]^T
    int t2 = t - 192;
    src = wo; dst = woT; C = 512; Rout = 512;
    r0 = (t2 >> 3) * 64; c0 = (t2 & 7) * 64;
  } else if (t < 512) {  // w1 [512][2048] -> [2048][512]
    int t2 = t - 256;
    src = w1; dst = w1T; C = 2048; Rout = 512;
    r0 = (t2 >> 5) * 64; c0 = (t2 & 31) * 64;
  } else {  // w2 [2048][512] -> [512][2048]
    int t2 = t - 512;
    src = w2; dst = w2T; C = 512; Rout = 2048;
    r0 = (t2 >> 3) * 64; c0 = (t2 & 7) * 64;
  }
#pragma unroll
  for (int j = 0; j < 4; ++j) {
    int e = j * 256 + tid;
    int r = e >> 4, c4 = e & 15;
    float4 f = *(const float4*)(src + (size_t)(r0 + r) * C + c0 + c4 * 4);
    tile[r][c4 * 4 + 0] = f.x;
    tile[r][c4 * 4 + 1] = f.y;
    tile[r][c4 * 4 + 2] = f.z;
    tile[r][c4 * 4 + 3] = f.w;
  }
  __syncthreads();
  const int co = tid >> 2, rr0 = (tid & 3) * 16;
  bf16x8 o0, o1;
#pragma unroll
  for (int k = 0; k < 8; ++k) o0[k] = (bf16)tile[rr0 + k][co];
#pragma unroll
  for (int k = 0; k < 8; ++k) o1[k] = (bf16)tile[rr0 + 8 + k][co];
  bf16* dp = dst + (size_t)(c0 + co) * Rout + r0 + rr0;
  *(bf16x8*)dp = o0;
  *(bf16x8*)(dp + 8) = o1;
}

// V^T extract: qkv [4096][1536] (V at col 1024+h*64) -> vtb [bh][64 dh][2048 s]
__global__ __launch_bounds__(256) void vtrans_k(const bf16* __restrict__ qkv,
                                                bf16* __restrict__ vtb) {
  __shared__ bf16 tile[64 * 68];
  const int tid = threadIdx.x;
  const int s0 = blockIdx.x * 64;
  const int bh = blockIdx.y, b = bh >> 3, hh = bh & 7;
  const bf16* src = qkv + 1024 + hh * 64;
#pragma unroll
  for (int j = 0; j < 2; ++j) {
    int slot = j * 256 + tid;
    int r = slot >> 3, cc = slot & 7;
    *(bf16x8*)(tile + r * 68 + cc * 8) =
        *(const bf16x8*)(src + (size_t)(b * 2048 + s0 + r) * 1536 + cc * 8);
  }
  __syncthreads();
  const int w = tid >> 6, lane = tid & 63;
#pragma unroll
  for (int sb2 = 0; sb2 < 2; ++sb2) {
    int sb = w * 2 + sb2;
    bf16x8 v;
#pragma unroll
    for (int jj = 0; jj < 8; ++jj) v[jj] = tile[(sb * 8 + jj) * 68 + lane];
    *(bf16x8*)(vtb + (size_t)bh * 131072 + (size_t)lane * 2048 + s0 + sb * 8) = v;
  }
}

// ---------------- 128x64 tile GEMM, dbuf + COUNTED vmcnt pipeline, optional split-K ----------------
// C[M][N] = A[M][K] * Bt[N][K]^T ; grid (M/128, N/64, nsplit), klen = K/nsplit
// Per K-step: vmcnt(6) [next tile stays in flight] -> barrier -> MFMA(buf d)
//             -> barrier -> stage(t+2 -> buf d). 6 = gll16 instrs/wave/tile.
// EPI 0: f32 partial out (NO bias), slice z at outf + z*M*N
// EPI 1: bf16 relu(acc+bias)
// EPI 2: bf16 acc+bias, cols<512 scaled by 1/8 (QKV fused Q-scale)
template <int EPI>
__global__ __launch_bounds__(256) void gemmN64(
    const bf16* __restrict__ A, const bf16* __restrict__ Bt,
    const float* __restrict__ bias, float* __restrict__ outf,
    bf16* __restrict__ outb, int M, int N, int K, int klen) {
  __shared__ bf16 As[2][128 * 64];
  __shared__ bf16 Bs[2][64 * 64];
  const int tid = threadIdx.x;
  const int w = tid >> 6, l = tid & 63;
  const int lh = l & 15, lg = l >> 4;
  const int m0 = blockIdx.x * 128, n0 = blockIdx.y * 64;
  const int k0 = blockIdx.z * klen;
  const int mb = (w & 1) * 64, nb = (w >> 1) * 32;
  f32x4 acc[4][2] = {};
  auto stage = [&](int kt, int d) {
#pragma unroll
    for (int j = 0; j < 4; ++j) {
      int slot = j * 256 + tid;
      int r = slot >> 3, cc = slot & 7;
      int kk = kt + ((cc ^ (r & 7)) << 3);  // swizzle SOURCE, LDS stays linear
      gll16(A + (size_t)(m0 + r) * K + kk, As[d] + slot * 8);
    }
#pragma unroll
    for (int j = 0; j < 2; ++j) {
      int slot = j * 256 + tid;
      int r = slot >> 3, cc = slot & 7;
      int kk = kt + ((cc ^ (r & 7)) << 3);
      gll16(Bt + (size_t)(n0 + r) * K + kk, Bs[d] + slot * 8);
    }
  };
  const int nsteps = klen >> 6;
  stage(k0, 0);                       // 6 in flight
  if (nsteps > 1) stage(k0 + 64, 1);  // 12 in flight
  for (int s = 0; s < nsteps; ++s) {
    const int d = s & 1;
    if (s + 1 < nsteps) { VMCNT(6); } else { VMCNT(0); }  // tile s retired; s+1 stays in flight
    __builtin_amdgcn_s_barrier();
    __builtin_amdgcn_sched_barrier(0);
    __builtin_amdgcn_s_setprio(1);
#pragma unroll
    for (int kk = 0; kk < 2; ++kk) {
      bf16x8 af[4], bfr[2];
#pragma unroll
      for (int mi = 0; mi < 4; ++mi) {
        int r = mb + mi * 16 + lh;
        af[mi] = *(const bf16x8*)(As[d] + r * 64 + (((kk * 4 + lg) ^ (r & 7)) << 3));
      }
#pragma unroll
      for (int ni = 0; ni < 2; ++ni) {
        int r = nb + ni * 16 + lh;
        bfr[ni] = *(const bf16x8*)(Bs[d] + r * 64 + (((kk * 4 + lg) ^ (r & 7)) << 3));
      }
#pragma unroll
      for (int mi = 0; mi < 4; ++mi)
#pragma unroll
        for (int ni = 0; ni < 2; ++ni)
          acc[mi][ni] = mfma16(af[mi], bfr[ni], acc[mi][ni]);
    }
    __builtin_amdgcn_s_setprio(0);
    __builtin_amdgcn_sched_barrier(0);
    __builtin_amdgcn_s_barrier();  // all waves done READING buf d (reads consumed pre-barrier)
    if (s + 2 < nsteps) stage(k0 + (s + 2) * 64, d);  // overwrite buf d for tile s+2
  }
  float* op = (EPI == 0) ? outf + (size_t)blockIdx.z * M * N : nullptr;
#pragma unroll
  for (int mi = 0; mi < 4; ++mi)
#pragma unroll
    for (int ni = 0; ni < 2; ++ni)
#pragma unroll
      for (int i = 0; i < 4; ++i) {
        int row = m0 + mb + mi * 16 + lg * 4 + i;  // C/D: col=lane&15, row=(lane>>4)*4+reg
        int col = n0 + nb + ni * 16 + lh;
        float v = acc[mi][ni][i];
        if (EPI == 0) {
          op[(size_t)row * N + col] = v;
        } else if (EPI == 1) {
          v += bias[col];
          outb[(size_t)row * N + col] = (bf16)fmaxf(v, 0.f);
        } else {
          v += bias[col];
          outb[(size_t)row * N + col] = (bf16)(col < 512 ? v * 0.125f : v);
        }
      }
}

// ---------------- flash attention fwd ----------------
// grid (16 qtiles, 16 bh); 8 waves. Waves 0-3: keys [0,1024), waves 4-7: [1024,2048),
// pair (w, w+4) shares q-rows qtile*128 + (w&3)*32 .. +32. 32x32x16 MFMA,
// swapped QK^T (S^T = K·Q^T), in-register softmax, P via cvt_pk+permlane32_swap.
__global__ __launch_bounds__(512) void attn_fwd2(
    const bf16* __restrict__ qkv,  // [4096][1536], Q pre-scaled by 1/8
    const bf16* __restrict__ vtb,  // [bh][64][2048]
    bf16* __restrict__ Y) {        // [4096][512]
  __shared__ __align__(16) char lds[65536];
  const int tid = threadIdx.x;
  const int w = tid >> 6, lane = tid & 63;
  const int l31 = lane & 31, h = lane >> 5;
  const int bh = blockIdx.y, b = bh >> 3, hh = bh & 7;
  const int qtile = blockIdx.x;
  const int half = w >> 2, wp = w & 3;
  const int q0 = qtile * 128 + wp * 32;
  const int tl = tid & 255, sh = tid >> 8;

  // Q B-frags: qf[g] = Q[q0+l31][g*16 + h*8 .. +8]
  bf16x8 qf[4];
  {
    const size_t rowQ = (size_t)(b * 2048 + q0 + l31) * 1536 + hh * 64;
#pragma unroll
    for (int g = 0; g < 4; ++g)
      qf[g] = *(const bf16x8*)(qkv + rowQ + g * 16 + h * 8);
  }
  const bf16* Kp = qkv + 512 + hh * 64;
  const bf16* Vp = vtb + (size_t)bh * 131072;

  f32x16 oacc[2] = {};
  float m_run = -1e30f, l_run = 0.f;

#define KBUF(d, hf) ((bf16*)(lds + (d) * 32768 + (hf) * 16384))
#define VBUF(d, hf) ((bf16*)(lds + (d) * 32768 + (hf) * 16384 + 8192))

  // stage iteration i into dbuf d (each half stages its own K,V^T 64x64 tiles)
  auto stage = [&](int i, int d) {
    const int k0 = sh * 1024 + i * 64;
#pragma unroll
    for (int j = 0; j < 2; ++j) {
      int slot = j * 256 + tl;
      int r = slot >> 3, cc = slot & 7;
      gll16(Kp + (size_t)(b * 2048 + k0 + r) * 1536 + ((cc ^ (r & 7)) << 3),
            KBUF(d, sh) + slot * 8);
      gll16(Vp + (size_t)r * 2048 + k0 + ((cc ^ (r & 7)) << 3),
            VBUF(d, sh) + slot * 8);
    }
  };

  stage(0, 0);
  __syncthreads();
  for (int i = 0; i < 16; ++i) {
    const int d = i & 1;
    if (i < 15) stage(i + 1, d ^ 1);
    const bf16* Kt = KBUF(d, half);
    const bf16* Vt = VBUF(d, half);
    // S^T tiles [32 keys x 32 q], keys kt*32 + (r&3)+8*(r>>2)+4h
    f32x16 st[2];
    __builtin_amdgcn_s_setprio(1);
#pragma unroll
    for (int kt = 0; kt < 2; ++kt) {
      f32x16 z = {};
      const int r = kt * 32 + l31;
#pragma unroll
      for (int g = 0; g < 4; ++g) {
        bf16x8 kf = *(const bf16x8*)(Kt + r * 64 + (((2 * g + h) ^ (r & 7)) << 3));
        z = mfma32(kf, qf[g], z);
      }
      st[kt] = z;
    }
    __builtin_amdgcn_s_setprio(0);
    // online softmax over 64 keys (32 regs/lane + cross-half)
    float mx = -1e30f;
#pragma unroll
    for (int kt = 0; kt < 2; ++kt)
#pragma unroll
      for (int r = 0; r < 16; ++r) mx = fmaxf(mx, st[kt][r]);
    mx = fmaxf(mx, __shfl_xor(mx, 32, 64));
    const float m_new = fmaxf(m_run, mx);
    const float scl = __expf(m_run - m_new);
    m_run = m_new;
    float ps = 0.f;
#pragma unroll
    for (int kt = 0; kt < 2; ++kt)
#pragma unroll
      for (int r = 0; r < 16; ++r) {
        float e = __expf(st[kt][r] - m_new);
        st[kt][r] = e;
        ps += e;
      }
    ps += __shfl_xor(ps, 32, 64);
    l_run = l_run * scl + ps;
    oacc[0] = oacc[0] * scl;
    oacc[1] = oacc[1] * scl;
    // pack P^T B-frags: per 16-key group, dwords {a0,a1,b0,b1}
    // pl32swap(a,b): a.hi <-> b.lo  =>  a: h0 keeps (0,1), h1 gets (8,9);
    //                                   b: h0 gets (4,5), h1 keeps (12,13).
    bf16x8 pf[4];
#pragma unroll
    for (int kt = 0; kt < 2; ++kt)
#pragma unroll
      for (int g = 0; g < 2; ++g) {
        unsigned a0 = cvtpk(st[kt][8 * g + 0], st[kt][8 * g + 1]);
        unsigned a1 = cvtpk(st[kt][8 * g + 2], st[kt][8 * g + 3]);
        unsigned b0 = cvtpk(st[kt][8 * g + 4], st[kt][8 * g + 5]);
        unsigned b1 = cvtpk(st[kt][8 * g + 6], st[kt][8 * g + 7]);
        pl32swap(a0, b0);
        pl32swap(a1, b1);
        union { unsigned u[4]; bf16x8 v; } pk;
        pk.u[0] = a0; pk.u[1] = a1; pk.u[2] = b0; pk.u[3] = b1;
        pf[kt * 2 + g] = pk.v;
      }
    // PV: Y^T[dh][q] += V^T frag x P frag
    __builtin_amdgcn_s_setprio(1);
#pragma unroll
    for (int t = 0; t < 2; ++t) {
      const int r = t * 32 + l31;
#pragma unroll
      for (int kg = 0; kg < 4; ++kg) {
        bf16x8 vf = *(const bf16x8*)(Vt + r * 64 + (((2 * kg + h) ^ (r & 7)) << 3));
        oacc[t] = mfma32(vf, pf[kg], oacc[t]);
      }
    }
    __builtin_amdgcn_s_setprio(0);
    __syncthreads();
  }

  // ---- merge split-KV halves ----
  // lds reuse: Ost [pair p][8 chunks][64 lanes][16B] @0 (32KB); m,l @32768 (2KB); Ytile @34816
  if (half == 1) {
    char* ob = lds + wp * 8192;
#pragma unroll
    for (int t = 0; t < 2; ++t)
#pragma unroll
      for (int c = 0; c < 4; ++c) {
        f32x4 v4 = {oacc[t][c * 4 + 0], oacc[t][c * 4 + 1],
                    oacc[t][c * 4 + 2], oacc[t][c * 4 + 3]};
        *(f32x4*)(ob + (t * 4 + c) * 1024 + lane * 16) = v4;
      }
    ((float2*)(lds + 32768))[wp * 64 + lane] = make_float2(m_run, l_run);
  }
  __syncthreads();
  bf16* Yt = (bf16*)(lds + 34816);  // [128 q][72 dh]
  if (half == 0) {
    float2 ml2 = ((const float2*)(lds + 32768))[wp * 64 + lane];
    const float mstar = fmaxf(m_run, ml2.x);
    const float e1 = __expf(m_run - mstar), e2 = __expf(ml2.x - mstar);
    const float lstar = l_run * e1 + ml2.y * e2;
    const float r1 = e1 / lstar, r2 = e2 / lstar;
    const char* ob = lds + wp * 8192;
#pragma unroll
    for (int t = 0; t < 2; ++t)
#pragma unroll
      for (int c = 0; c < 4; ++c) {
        f32x4 v4 = *(const f32x4*)(ob + (t * 4 + c) * 1024 + lane * 16);
#pragma unroll
        for (int j = 0; j < 4; ++j)
          oacc[t][c * 4 + j] = oacc[t][c * 4 + j] * r1 + v4[j] * r2;
      }
#pragma unroll
    for (int t = 0; t < 2; ++t)
#pragma unroll
      for (int r = 0; r < 16; ++r) {
        int dh = (r & 3) + 8 * (r >> 2) + 4 * h + 32 * t;
        Yt[(wp * 32 + l31) * 72 + dh] = (bf16)oacc[t][r];
      }
  }
  __syncthreads();
#pragma unroll
  for (int it = 0; it < 2; ++it) {
    int s = it * 512 + tid;
    int ql = s >> 3, cbk = s & 7;
    bf16x8 v = *(const bf16x8*)(Yt + ql * 72 + cbk * 8);
    *(bf16x8*)(Y + (size_t)(b * 2048 + qtile * 128 + ql) * 512 + hh * 64 + cbk * 8) = v;
  }
#undef KBUF
#undef VBUF
}

// ---------------- fused: sum 2 split-K partials + bias + f32 residual -> LN -> bf16 ----------------
__global__ __launch_bounds__(256) void add_ln1_k(
    const float* __restrict__ P,  // [2][4096][512]
    const float* __restrict__ xres, const float* __restrict__ bias,
    const float* __restrict__ gamma, const float* __restrict__ beta,
    bf16* __restrict__ outb) {
  const int row = blockIdx.x, tid = threadIdx.x;
  const size_t base = (size_t)row * 512;
  const float2 p0 = ((const float2*)(P + base))[tid];
  const float2 p1 = ((const float2*)(P + 2097152 + base))[tid];
  const float2 xr = ((const float2*)(xres + base))[tid];
  const int c = tid * 2;
  float s0 = p0.x + p1.x + bias[c] + xr.x;
  float s1 = p0.y + p1.y + bias[c + 1] + xr.y;
  float sum = s0 + s1;
#pragma unroll
  for (int m = 1; m < 64; m <<= 1) sum += __shfl_xor(sum, m, 64);
  __shared__ float part[4], part2[4];
  const int w = tid >> 6, l = tid & 63;
  if (l == 0) part[w] = sum;
  __syncthreads();
  const float mean = (part[0] + part[1] + part[2] + part[3]) * (1.f / 512.f);
  const float d0 = s0 - mean, d1 = s1 - mean;
  float vs = d0 * d0 + d1 * d1;
#pragma unroll
  for (int m = 1; m < 64; m <<= 1) vs += __shfl_xor(vs, m, 64);
  if (l == 0) part2[w] = vs;
  __syncthreads();
  const float var = (part2[0] + part2[1] + part2[2] + part2[3]) * (1.f / 512.f);
  const float inv = rsqrtf(var);
  outb[base + c] = (bf16)(gamma[c] * (d0 * inv) + beta[c]);
  outb[base + c + 1] = (bf16)(gamma[c + 1] * (d1 * inv) + beta[c + 1]);
}

// ---------------- fused: sum 2 partials + bias + bf16 residual -> LN -> f32 out ----------------
__global__ __launch_bounds__(256) void add_ln2_k(
    const float* __restrict__ P,  // [2][4096][512]
    const bf16* __restrict__ rres, const float* __restrict__ bias,
    const float* __restrict__ gamma, const float* __restrict__ beta,
    float* __restrict__ outf) {
  const int row = blockIdx.x, tid = threadIdx.x;
  const size_t base = (size_t)row * 512;
  const float2 p0 = ((const float2*)(P + base))[tid];
  const float2 p1 = ((const float2*)(P + 2097152 + base))[tid];
  const int c = tid * 2;
  float s0 = p0.x + p1.x + bias[c] + (float)rres[base + c];
  float s1 = p0.y + p1.y + bias[c + 1] + (float)rres[base + c + 1];
  float sum = s0 + s1;
#pragma unroll
  for (int m = 1; m < 64; m <<= 1) sum += __shfl_xor(sum, m, 64);
  __shared__ float part[4], part2[4];
  const int w = tid >> 6, l = tid & 63;
  if (l == 0) part[w] = sum;
  __syncthreads();
  const float mean = (part[0] + part[1] + part[2] + part[3]) * (1.f / 512.f);
  const float d0 = s0 - mean, d1 = s1 - mean;
  float vs = d0 * d0 + d1 * d1;
#pragma unroll
  for (int m = 1; m < 64; m <<= 1) vs += __shfl_xor(vs, m, 64);
  if (l == 0) part2[w] = vs;
  __syncthreads();
  const float var = (part2[0] + part2[1] + part2[2] + part2[3]) * (1.f / 512.f);
  const float inv = rsqrtf(var);
  ((float2*)(outf + base))[tid] =
      make_float2(gamma[c] * (d0 * inv) + beta[c], gamma[c + 1] * (d1 * inv) + beta[c + 1]);
}

// ---------------- launch ----------------
extern "C" void kernel_launch(void* const* d_in, const int* in_sizes, int n_in,
                              void* d_out, int out_size, void* d_ws, size_t ws_size,
                              hipStream_t stream) {
  const float* x = (const float*)d_in[0];
  const float* wq = (const float*)d_in[1];
  const float* bq = (const float*)d_in[2];
  const float* wk = (const float*)d_in[3];
  const float* bk = (const float*)d_in[4];
  const float* wv = (const float*)d_in[5];
  const float* bv = (const float*)d_in[6];
  const float* wo = (const float*)d_in[7];
  const float* bo = (const float*)d_in[8];
  const float* g1 = (const float*)d_in[9];
  const float* be1 = (const float*)d_in[10];
  const float* w1 = (const float*)d_in[11];
  const float* b1 = (const float*)d_in[12];
  const float* w2 = (const float*)d_in[13];
  const float* b2 = (const float*)d_in[14];
  const float* g2 = (const float*)d_in[15];
  const float* be2 = (const float*)d_in[16];

  char* ws = (char*)d_ws;
  // layout (aliasing by liveness):
  bf16* xb    = (bf16*)(ws + 0);          // 4MB, cast -> QKV gemm
  bf16* y1b   = (bf16*)(ws + 0);          // 4MB, LN1 out -> FFN1 in, LN2 residual (aliases xb)
  bf16* wqkvT = (bf16*)(ws + 4194304);    // 1.5MB [1536][512]
  bf16* woT   = (bf16*)(ws + 5767168);    // 0.5MB
  bf16* w1T   = (bf16*)(ws + 6291456);    // 2MB
  bf16* w2T   = (bf16*)(ws + 8388608);    // 2MB
  float* cb   = (float*)(ws + 10485760);  // 8KB
  bf16* qkvb  = (bf16*)(ws + 10493952);   // 12MB [4096][1536], QKV -> attn
  float* t0   = (float*)(ws + 10493952);  // 16MB [2][4096][512] O-proj partials (alias qkvb, post-attn)
  bf16* f1    = (bf16*)(ws + 10493952);   // 16MB [4096][2048] FFN1 out (alias t0, post-LN1)
  bf16* vtb   = (bf16*)(ws + 23078656);   // 4MB [16][64][2048], vtrans -> attn
  bf16* yb    = (bf16*)(ws + 27272960);   // 4MB [4096][512], attn -> O-proj
  float* f2   = (float*)(ws + 27272960);  // 16MB [2][4096][512] FFN2 partials (alias yb, post-Oproj)

  prep_k<<<1793, 256, 0, stream>>>(x, wq, wk, wv, wo, w1, w2, bq, bk, bv,
                                   xb, wqkvT, woT, w1T, w2T, cb);

  // QKV: 768 blocks
  gemmN64<2><<<dim3(32, 24, 1), 256, 0, stream>>>(xb, wqkvT, cb, nullptr, qkvb,
                                                  4096, 1536, 512, 512);
  vtrans_k<<<dim3(32, 16), 256, 0, stream>>>(qkvb, vtb);
  attn_fwd2<<<dim3(16, 16), 512, 0, stream>>>(qkvb, vtb, yb);
  // O-proj: split-K x2, 512 blocks, partials (bias added in LN1)
  gemmN64<0><<<dim3(32, 8, 2), 256, 0, stream>>>(yb, woT, nullptr, t0, nullptr,
                                                 4096, 512, 512, 256);
  add_ln1_k<<<4096, 256, 0, stream>>>(t0, x, bo, g1, be1, y1b);
  // FFN1: 1024 blocks
  gemmN64<1><<<dim3(32, 32, 1), 256, 0, stream>>>(y1b, w1T, b1, nullptr, f1,
                                                  4096, 2048, 512, 512);
  // FFN2: split-K x2, 512 blocks, partials (bias added in LN2)
  gemmN64<0><<<dim3(32, 8, 2), 256, 0, stream>>>(f1, w2T, nullptr, f2, nullptr,
                                                 4096, 512, 2048, 1024);
  add_ln2_k<<<4096, 256, 0, stream>>>(f2, y1b, b2, g2, be2, (float*)d_out);
}